// Round 4
// baseline (1775.555 us; speedup 1.0000x reference)
//
#include <hip/hip_runtime.h>
#include <hip/hip_fp16.h>
#include <stdint.h>

#define B_ROWS 4096
#define D_IN   1024
#define D_HID  2048
#define D_OUT  1024
#define NEXP   8
#define NCH    3

typedef _Float16 f16;
typedef __attribute__((ext_vector_type(4))) _Float16 f16x4;
typedef __attribute__((ext_vector_type(8))) _Float16 f16x8;
typedef __attribute__((ext_vector_type(4))) float f32x4;

typedef __attribute__((address_space(1))) const void gvoid_t;
typedef __attribute__((address_space(3))) void lvoid_t;

__device__ __forceinline__ void glds16(const void* g, void* l) {
  // async global->LDS, 16B per lane; LDS dest = wave-uniform base + lane*16
  __builtin_amdgcn_global_load_lds((gvoid_t*)g, (lvoid_t*)l, 16, 0, 0);
}

// ---------------- gates: softmax(inp @ Wg) in exact fp32, one wave per row ----
__global__ __launch_bounds__(256) void gates_kernel(
    const float* __restrict__ x, const float* __restrict__ y, const float* __restrict__ z,
    const float* __restrict__ Wg1, const float* __restrict__ Wg2, const float* __restrict__ Wg3,
    float* __restrict__ gates) {
  int wave = blockIdx.x * 4 + (threadIdx.x >> 6);
  int lane = threadIdx.x & 63;
  int c = wave >> 12;          // /4096
  int b = wave & 4095;
  const float* inp = (c == 0) ? x : (c == 1) ? y : z;
  const float* Wg  = (c == 0) ? Wg1 : (c == 1) ? Wg2 : Wg3;
  const float* row = inp + (size_t)b * D_IN;
  float acc[8];
#pragma unroll
  for (int e = 0; e < 8; ++e) acc[e] = 0.f;
  for (int k = lane; k < D_IN; k += 64) {
    float xv = row[k];
    const float* w = Wg + (size_t)k * 8;
#pragma unroll
    for (int e = 0; e < 8; ++e) acc[e] += xv * w[e];
  }
#pragma unroll
  for (int off = 32; off > 0; off >>= 1) {
#pragma unroll
    for (int e = 0; e < 8; ++e) acc[e] += __shfl_xor(acc[e], off, 64);
  }
  if (lane == 0) {
    float m = acc[0];
#pragma unroll
    for (int e = 1; e < 8; ++e) m = fmaxf(m, acc[e]);
    float s = 0.f, ex[8];
#pragma unroll
    for (int e = 0; e < 8; ++e) { ex[e] = expf(acc[e] - m); s += ex[e]; }
    float inv = 1.f / s;
    float* go = gates + (size_t)(c * B_ROWS + b) * 8;
#pragma unroll
    for (int e = 0; e < 8; ++e) go[e] = ex[e] * inv;
  }
}

// ---------------- fp32 -> fp16 streaming convert (x/y/z) ----------------------
__global__ __launch_bounds__(256) void conv_inp(const float* __restrict__ in,
                                                f16* __restrict__ o) {
  int i = (blockIdx.x * 256 + threadIdx.x) * 4;
  float4 v = *(const float4*)(in + i);
  f16x4 p = {(f16)v.x, (f16)v.y, (f16)v.z, (f16)v.w};
  *(f16x4*)(o + i) = p;
}

// ---------------- fp32 [K][N] -> fp16 [N][K] transpose-convert ----------------
__global__ __launch_bounds__(256) void conv_transpose(const float* __restrict__ W,
                                                      f16* __restrict__ Wt,
                                                      int K, int N) {
  W  += (size_t)blockIdx.z * K * N;
  Wt += (size_t)blockIdx.z * K * N;
  int n0 = blockIdx.x * 64, k0 = blockIdx.y * 64;
  __shared__ f16 t[64][72];
  int tid = threadIdx.x;
  int rr = tid >> 4;            // 0..15
  int cq = (tid & 15) * 4;      // 0..60
#pragma unroll
  for (int it = 0; it < 4; ++it) {
    int r = rr + it * 16;
    float4 v = *(const float4*)(W + (size_t)(k0 + r) * N + n0 + cq);
    t[r][cq + 0] = (f16)v.x; t[r][cq + 1] = (f16)v.y;
    t[r][cq + 2] = (f16)v.z; t[r][cq + 3] = (f16)v.w;
  }
  __syncthreads();
#pragma unroll
  for (int it = 0; it < 2; ++it) {
    int idx = tid + it * 256;
    int nr = idx >> 3;          // 0..63
    int kq = (idx & 7) * 8;     // 0..56
    f16x8 o;
#pragma unroll
    for (int j = 0; j < 8; ++j) o[j] = t[kq + j][nr];
    *(f16x8*)(Wt + (size_t)(n0 + nr) * K + k0 + kq) = o;
  }
}

// ---------------- GEMM1: H[e] = relu(x @ W1[e] + b1[e]) * g[:,e]  -------------
// A fp16 [rows][1024]; Bt fp16 n-major [ge][2048][1024]; out fp16 [ge][rows][2048]
__global__ __launch_bounds__(256, 2) void gemm1_kernel(
    const f16* __restrict__ A, const f16* __restrict__ Bt,
    const float* __restrict__ b1, const float* __restrict__ gch,
    f16* __restrict__ H, int e0, int hrows) {
  const int K = D_IN, NK = D_IN / 32;
  int ez = blockIdx.z, e = e0 + ez;
  const f16* Be = Bt + (size_t)ez * D_HID * D_IN;
  f16* He = H + (size_t)ez * (size_t)hrows * D_HID;
  int m0 = blockIdx.x * 128, n0 = blockIdx.y * 128;
  int tid = threadIdx.x, wid = tid >> 6, lane = tid & 63;
  int wr = wid >> 1, wc = wid & 1;

  __shared__ __align__(16) f16 sA[2][128 * 32];
  __shared__ __align__(16) f16 sB[2][128 * 32];

  // staging: 8 chunks of 16 rows each for A and B; wave w owns chunks 2w,2w+1.
  // XOR-swizzle kq^(row&3) applied on the GLOBAL source (rule #21), LDS linear.
  int kq = lane & 3;
  int ra0 = (wid * 2 + 0) * 16 + (lane >> 2);
  int ra1 = (wid * 2 + 1) * 16 + (lane >> 2);
  const f16* gA0 = A  + (size_t)(m0 + ra0) * K + ((kq ^ (ra0 & 3)) * 8);
  const f16* gA1 = A  + (size_t)(m0 + ra1) * K + ((kq ^ (ra1 & 3)) * 8);
  const f16* gB0 = Be + (size_t)(n0 + ra0) * K + ((kq ^ (ra0 & 3)) * 8);
  const f16* gB1 = Be + (size_t)(n0 + ra1) * K + ((kq ^ (ra1 & 3)) * 8);

  f32x4 zz = {0.f, 0.f, 0.f, 0.f};
  f32x4 acc[4][4];
#pragma unroll
  for (int i = 0; i < 4; ++i)
#pragma unroll
    for (int j = 0; j < 4; ++j) acc[i][j] = zz;

  int arow = wr * 64 + (lane & 15);
  int bcol = wc * 64 + (lane & 15);
  int kblk = lane >> 4;
  int aoff = arow * 32 + ((kblk ^ (arow & 3)) * 8);
  int boff = bcol * 32 + ((kblk ^ (bcol & 3)) * 8);

  auto stage = [&](int kt, int buf) {
    int ko = kt * 32;
    glds16(gA0 + ko, &sA[buf][(wid * 2 + 0) * 512]);
    glds16(gA1 + ko, &sA[buf][(wid * 2 + 1) * 512]);
    glds16(gB0 + ko, &sB[buf][(wid * 2 + 0) * 512]);
    glds16(gB1 + ko, &sB[buf][(wid * 2 + 1) * 512]);
  };

  stage(0, 0);
  __syncthreads();
  for (int kt = 0; kt < NK; ++kt) {
    int buf = kt & 1;
    if (kt + 1 < NK) stage(kt + 1, buf ^ 1);
    f16x8 af[4], bf[4];
#pragma unroll
    for (int i = 0; i < 4; ++i) {
      af[i] = *(const f16x8*)&sA[buf][aoff + i * 512];
      bf[i] = *(const f16x8*)&sB[buf][boff + i * 512];
    }
#pragma unroll
    for (int mi = 0; mi < 4; ++mi)
#pragma unroll
      for (int ni = 0; ni < 4; ++ni)
        acc[mi][ni] = __builtin_amdgcn_mfma_f32_16x16x32_f16(af[mi], bf[ni], acc[mi][ni], 0, 0, 0);
    __syncthreads();
  }

  float bv[4];
#pragma unroll
  for (int ni = 0; ni < 4; ++ni)
    bv[ni] = b1[(size_t)e * D_HID + n0 + wc * 64 + ni * 16 + (lane & 15)];
  int colb = n0 + wc * 64 + (lane & 15);
#pragma unroll
  for (int mi = 0; mi < 4; ++mi) {
#pragma unroll
    for (int r = 0; r < 4; ++r) {
      int grow = m0 + wr * 64 + mi * 16 + (lane >> 4) * 4 + r;
      float gv = gch[(size_t)grow * 8 + e];
      f16* hp = He + (size_t)grow * D_HID + colb;
#pragma unroll
      for (int ni = 0; ni < 4; ++ni) {
        float h = acc[mi][ni][r] + bv[ni];
        h = h > 0.f ? h : 0.f;
        hp[ni * 16] = (f16)(h * gv);
      }
    }
  }
}

// ---------------- GEMM2: out[:,c] (+)= sum_e (gH_e) @ W2[e] + g_e*b2[e] -------
// A fp16 [ge][hrows][2048]; Bt fp16 n-major [ge][1024][2048]
// Same 128x128 / 4-wave / 4x4 structure as gemm1; experts flattened into K sweep.
__global__ __launch_bounds__(256, 2) void gemm2_kernel(
    const f16* __restrict__ H, const f16* __restrict__ Bt,
    const float* __restrict__ b2, const float* __restrict__ gch,
    float* __restrict__ out, int e0, int ge, int cbase, int accflag, int hrows) {
  const int K = D_HID;
  int m0 = blockIdx.x * 128, n0 = blockIdx.y * 128;
  int tid = threadIdx.x, wid = tid >> 6, lane = tid & 63;
  int wr = wid >> 1, wc = wid & 1;

  __shared__ __align__(16) f16 sA[2][128 * 32];
  __shared__ __align__(16) f16 sB[2][128 * 32];

  int kq = lane & 3;
  int ra0 = (wid * 2 + 0) * 16 + (lane >> 2);
  int ra1 = (wid * 2 + 1) * 16 + (lane >> 2);
  size_t oA0 = (size_t)(m0 + ra0) * K + ((kq ^ (ra0 & 3)) * 8);
  size_t oA1 = (size_t)(m0 + ra1) * K + ((kq ^ (ra1 & 3)) * 8);
  size_t oB0 = (size_t)(n0 + ra0) * K + ((kq ^ (ra0 & 3)) * 8);
  size_t oB1 = (size_t)(n0 + ra1) * K + ((kq ^ (ra1 & 3)) * 8);
  const size_t EA = (size_t)hrows * D_HID;
  const size_t EB = (size_t)D_OUT * D_HID;

  f32x4 zz = {0.f, 0.f, 0.f, 0.f};
  f32x4 acc[4][4];
#pragma unroll
  for (int i = 0; i < 4; ++i)
#pragma unroll
    for (int j = 0; j < 4; ++j) acc[i][j] = zz;

  int arow = wr * 64 + (lane & 15);
  int bcol = wc * 64 + (lane & 15);
  int kblk = lane >> 4;
  int aoff = arow * 32 + ((kblk ^ (arow & 3)) * 8);
  int boff = bcol * 32 + ((kblk ^ (bcol & 3)) * 8);

  int S = ge * (K / 32);   // experts flattened into the K sweep
  auto stage = [&](int s, int buf) {
    int ee = s >> 6; size_t ko = (size_t)(s & 63) * 32;
    glds16(H  + (size_t)ee * EA + oA0 + ko, &sA[buf][(wid * 2 + 0) * 512]);
    glds16(H  + (size_t)ee * EA + oA1 + ko, &sA[buf][(wid * 2 + 1) * 512]);
    glds16(Bt + (size_t)ee * EB + oB0 + ko, &sB[buf][(wid * 2 + 0) * 512]);
    glds16(Bt + (size_t)ee * EB + oB1 + ko, &sB[buf][(wid * 2 + 1) * 512]);
  };

  stage(0, 0);
  __syncthreads();
  for (int s = 0; s < S; ++s) {
    int buf = s & 1;
    if (s + 1 < S) stage(s + 1, buf ^ 1);
    f16x8 af[4], bf[4];
#pragma unroll
    for (int i = 0; i < 4; ++i) {
      af[i] = *(const f16x8*)&sA[buf][aoff + i * 512];
      bf[i] = *(const f16x8*)&sB[buf][boff + i * 512];
    }
#pragma unroll
    for (int mi = 0; mi < 4; ++mi)
#pragma unroll
      for (int ni = 0; ni < 4; ++ni)
        acc[mi][ni] = __builtin_amdgcn_mfma_f32_16x16x32_f16(af[mi], bf[ni], acc[mi][ni], 0, 0, 0);
    __syncthreads();
  }

  // stage b2 slice (ge x 128 cols) into now-free LDS: sb2[ee*128 + col_in_tile]
  // (safe: final K-iter __syncthreads drained all sA reads)
  float* sb2 = (float*)&sA[0][0];
  for (int i = tid; i < ge * 128; i += 256)
    sb2[i] = b2[(size_t)(e0 + (i >> 7)) * D_OUT + n0 + (i & 127)];
  __syncthreads();

  int cit = wc * 64 + (lane & 15);   // col in tile (+ ni*16)
#pragma unroll
  for (int mi = 0; mi < 4; ++mi) {
#pragma unroll
    for (int r = 0; r < 4; ++r) {
      int grow = m0 + wr * 64 + mi * 16 + (lane >> 4) * 4 + r;
      const float* gv = gch + (size_t)grow * 8;
      float* po = out + (size_t)grow * (NCH * D_OUT) + cbase + n0 + cit;
#pragma unroll
      for (int ni = 0; ni < 4; ++ni) {
        float bias = 0.f;
        for (int ee = 0; ee < ge; ++ee)
          bias += gv[e0 + ee] * sb2[ee * 128 + cit + ni * 16];
        float v = acc[mi][ni][r] + bias;
        if (accflag) po[ni * 16] += v; else po[ni * 16] = v;
      }
    }
  }
}

extern "C" void kernel_launch(void* const* d_in, const int* in_sizes, int n_in,
                              void* d_out, int out_size, void* d_ws, size_t ws_size,
                              hipStream_t stream) {
  const float* x   = (const float*)d_in[0];
  const float* y   = (const float*)d_in[1];
  const float* z   = (const float*)d_in[2];
  const float* W1  = (const float*)d_in[3];
  const float* b1  = (const float*)d_in[4];
  const float* W2  = (const float*)d_in[5];
  const float* b2  = (const float*)d_in[6];
  const float* Wg1 = (const float*)d_in[7];
  const float* Wg2 = (const float*)d_in[8];
  const float* Wg3 = (const float*)d_in[9];
  float* out = (float*)d_out;
  char* ws = (char*)d_ws;

  const size_t MB = (size_t)1 << 20;
  const size_t inpE = (size_t)B_ROWS * D_IN;               // elems per channel
  float* gates = (float*)ws;                               // 384 KB (pad to 512K)

  hipLaunchKernelGGL(gates_kernel, dim3(NCH * B_ROWS / 4), dim3(256), 0, stream,
                     x, y, z, Wg1, Wg2, Wg3, gates);

  size_t base = (512u << 10) + NCH * inpE * sizeof(f16);   // gates + 3ch inp16 ~24.5 MB
  size_t perE = 24 * MB;                                   // 4M W1t + 4M W2t + 16M H

  if (ws_size >= base + perE) {
    // ---------------- main path: full-height H, EG experts resident ----------
    f16* inp16 = (f16*)(ws + (512u << 10));
    int EG = (int)((ws_size - base) / perE);
    if (EG > NEXP) EG = NEXP;
    f16* W1t = (f16*)(ws + base);
    f16* W2t = (f16*)(ws + base + (size_t)EG * (4 * MB));
    f16* Hb  = (f16*)(ws + base + (size_t)EG * (8 * MB));

    hipLaunchKernelGGL(conv_inp, dim3(B_ROWS * D_IN / 1024), dim3(256), 0, stream, x, inp16);
    hipLaunchKernelGGL(conv_inp, dim3(B_ROWS * D_IN / 1024), dim3(256), 0, stream, y, inp16 + inpE);
    hipLaunchKernelGGL(conv_inp, dim3(B_ROWS * D_IN / 1024), dim3(256), 0, stream, z, inp16 + 2 * inpE);

    for (int e0 = 0; e0 < NEXP; e0 += EG) {
      int ge = (EG < NEXP - e0) ? EG : (NEXP - e0);
      hipLaunchKernelGGL(conv_transpose, dim3(D_HID / 64, D_IN / 64, ge), dim3(256), 0, stream,
                         W1 + (size_t)e0 * D_IN * D_HID, W1t, D_IN, D_HID);
      hipLaunchKernelGGL(conv_transpose, dim3(D_OUT / 64, D_HID / 64, ge), dim3(256), 0, stream,
                         W2 + (size_t)e0 * D_HID * D_OUT, W2t, D_HID, D_OUT);
      for (int c = 0; c < NCH; ++c) {
        const float* gch = gates + (size_t)c * B_ROWS * 8;
        hipLaunchKernelGGL(gemm1_kernel, dim3(32, 16, ge), dim3(256), 0, stream,
                           inp16 + (size_t)c * inpE, W1t, b1, gch, Hb, e0, B_ROWS);
        hipLaunchKernelGGL(gemm2_kernel, dim3(32, 8, 1), dim3(256), 0, stream,
                           Hb, W2t, b2, gch, out, e0, ge, c * D_OUT, e0 > 0 ? 1 : 0, B_ROWS);
      }
    }
  } else {
    // ---------------- fallback: row-chunked H, single expert resident --------
    // layout: gates(512K) | inp16buf(8M) | W1t(4M) | W2t(4M) | Hb(4M) = ~20.5MB
    const int CH = 1024;                                   // H chunk rows
    f16* inp16 = (f16*)(ws + (512u << 10));
    f16* W1t   = (f16*)(ws + (512u << 10) + 8 * MB);
    f16* W2t   = (f16*)(ws + (512u << 10) + 12 * MB);
    f16* Hb    = (f16*)(ws + (512u << 10) + 16 * MB);

    for (int c = 0; c < NCH; ++c) {
      const float* inp = c == 0 ? x : c == 1 ? y : z;
      const float* gch = gates + (size_t)c * B_ROWS * 8;
      hipLaunchKernelGGL(conv_inp, dim3(B_ROWS * D_IN / 1024), dim3(256), 0, stream, inp, inp16);
      for (int e = 0; e < NEXP; ++e) {
        hipLaunchKernelGGL(conv_transpose, dim3(D_HID / 64, D_IN / 64, 1), dim3(256), 0, stream,
                           W1 + (size_t)e * D_IN * D_HID, W1t, D_IN, D_HID);
        hipLaunchKernelGGL(conv_transpose, dim3(D_OUT / 64, D_HID / 64, 1), dim3(256), 0, stream,
                           W2 + (size_t)e * D_HID * D_OUT, W2t, D_HID, D_OUT);
        for (int mb = 0; mb < B_ROWS; mb += CH) {
          hipLaunchKernelGGL(gemm1_kernel, dim3(CH / 128, 16, 1), dim3(256), 0, stream,
                             inp16 + (size_t)mb * D_IN, W1t, b1, gch + (size_t)mb * 8,
                             Hb, e, CH);
          hipLaunchKernelGGL(gemm2_kernel, dim3(CH / 128, 8, 1), dim3(256), 0, stream,
                             Hb, W2t, b2, gch + (size_t)mb * 8,
                             out + (size_t)mb * (NCH * D_OUT), e, 1, c * D_OUT,
                             e > 0 ? 1 : 0, CH);
        }
      }
    }
  }
}

// Round 7
// 1309.889 us; speedup vs baseline: 1.3555x; 1.3555x over previous
//
#include <hip/hip_runtime.h>
#include <hip/hip_fp16.h>
#include <stdint.h>

#define B_ROWS 4096
#define D_IN   1024
#define D_HID  2048
#define D_OUT  1024
#define NEXP   8
#define NCH    3
#define MTOT   (B_ROWS * NCH)   // 12288 flattened rows

typedef _Float16 f16;
typedef __attribute__((ext_vector_type(4))) _Float16 f16x4;
typedef __attribute__((ext_vector_type(8))) _Float16 f16x8;
typedef __attribute__((ext_vector_type(4))) float f32x4;

typedef __attribute__((address_space(1))) const void gvoid_t;
typedef __attribute__((address_space(3))) void lvoid_t;

__device__ __forceinline__ void glds16(const void* g, void* l) {
  // async global->LDS, 16B per lane; LDS dest = wave-uniform base + lane*16
  __builtin_amdgcn_global_load_lds((gvoid_t*)g, (lvoid_t*)l, 16, 0, 0);
}

// ---------------- gates: softmax(inp @ Wg) in exact fp32, one wave per row ----
__global__ __launch_bounds__(256) void gates_kernel(
    const float* __restrict__ x, const float* __restrict__ y, const float* __restrict__ z,
    const float* __restrict__ Wg1, const float* __restrict__ Wg2, const float* __restrict__ Wg3,
    float* __restrict__ gates) {
  int wave = blockIdx.x * 4 + (threadIdx.x >> 6);
  int lane = threadIdx.x & 63;
  int c = wave >> 12;          // /4096
  int b = wave & 4095;
  const float* inp = (c == 0) ? x : (c == 1) ? y : z;
  const float* Wg  = (c == 0) ? Wg1 : (c == 1) ? Wg2 : Wg3;
  const float* row = inp + (size_t)b * D_IN;
  float acc[8];
#pragma unroll
  for (int e = 0; e < 8; ++e) acc[e] = 0.f;
  for (int k = lane; k < D_IN; k += 64) {
    float xv = row[k];
    const float* w = Wg + (size_t)k * 8;
#pragma unroll
    for (int e = 0; e < 8; ++e) acc[e] += xv * w[e];
  }
#pragma unroll
  for (int off = 32; off > 0; off >>= 1) {
#pragma unroll
    for (int e = 0; e < 8; ++e) acc[e] += __shfl_xor(acc[e], off, 64);
  }
  if (lane == 0) {
    float m = acc[0];
#pragma unroll
    for (int e = 1; e < 8; ++e) m = fmaxf(m, acc[e]);
    float s = 0.f, ex[8];
#pragma unroll
    for (int e = 0; e < 8; ++e) { ex[e] = expf(acc[e] - m); s += ex[e]; }
    float inv = 1.f / s;
    float* go = gates + (size_t)(c * B_ROWS + b) * 8;
#pragma unroll
    for (int e = 0; e < 8; ++e) go[e] = ex[e] * inv;
  }
}

// ---------------- fp32 -> fp16 streaming convert (x/y/z) ----------------------
__global__ __launch_bounds__(256) void conv_inp(const float* __restrict__ in,
                                                f16* __restrict__ o) {
  int i = (blockIdx.x * 256 + threadIdx.x) * 4;
  float4 v = *(const float4*)(in + i);
  f16x4 p = {(f16)v.x, (f16)v.y, (f16)v.z, (f16)v.w};
  *(f16x4*)(o + i) = p;
}

// ---------------- fp32 [K][N] -> fp16 [N][K] transpose-convert ----------------
__global__ __launch_bounds__(256) void conv_transpose(const float* __restrict__ W,
                                                      f16* __restrict__ Wt,
                                                      int K, int N) {
  W  += (size_t)blockIdx.z * K * N;
  Wt += (size_t)blockIdx.z * K * N;
  int n0 = blockIdx.x * 64, k0 = blockIdx.y * 64;
  __shared__ f16 t[64][72];
  int tid = threadIdx.x;
  int rr = tid >> 4;            // 0..15
  int cq = (tid & 15) * 4;      // 0..60
#pragma unroll
  for (int it = 0; it < 4; ++it) {
    int r = rr + it * 16;
    float4 v = *(const float4*)(W + (size_t)(k0 + r) * N + n0 + cq);
    t[r][cq + 0] = (f16)v.x; t[r][cq + 1] = (f16)v.y;
    t[r][cq + 2] = (f16)v.z; t[r][cq + 3] = (f16)v.w;
  }
  __syncthreads();
#pragma unroll
  for (int it = 0; it < 2; ++it) {
    int idx = tid + it * 256;
    int nr = idx >> 3;          // 0..63
    int kq = (idx & 7) * 8;     // 0..56
    f16x8 o;
#pragma unroll
    for (int j = 0; j < 8; ++j) o[j] = t[kq + j][nr];
    *(f16x8*)(Wt + (size_t)(n0 + nr) * K + k0 + kq) = o;
  }
}

// ---------------- GEMM1: H[e] = relu(x @ W1[e] + b1[e]) * g[:,e]  -------------
// A fp16 [hrows][1024]; Bt fp16 n-major [ge][2048][1024]; out fp16 [ge][hrows][2048]
__global__ __launch_bounds__(256, 2) void gemm1_kernel(
    const f16* __restrict__ A, const f16* __restrict__ Bt,
    const float* __restrict__ b1, const float* __restrict__ gch,
    f16* __restrict__ H, int e0, int hrows) {
  const int K = D_IN, NK = D_IN / 32;
  int ez = blockIdx.z, e = e0 + ez;
  const f16* Be = Bt + (size_t)ez * D_HID * D_IN;
  f16* He = H + (size_t)ez * (size_t)hrows * D_HID;
  int m0 = blockIdx.x * 128, n0 = blockIdx.y * 128;
  int tid = threadIdx.x, wid = tid >> 6, lane = tid & 63;
  int wr = wid >> 1, wc = wid & 1;

  __shared__ __align__(16) f16 sA[2][128 * 32];
  __shared__ __align__(16) f16 sB[2][128 * 32];

  // staging: 8 chunks of 16 rows each for A and B; wave w owns chunks 2w,2w+1.
  // XOR-swizzle kq^(row&3) applied on the GLOBAL source (rule #21), LDS linear.
  int kq = lane & 3;
  int ra0 = (wid * 2 + 0) * 16 + (lane >> 2);
  int ra1 = (wid * 2 + 1) * 16 + (lane >> 2);
  const f16* gA0 = A  + (size_t)(m0 + ra0) * K + ((kq ^ (ra0 & 3)) * 8);
  const f16* gA1 = A  + (size_t)(m0 + ra1) * K + ((kq ^ (ra1 & 3)) * 8);
  const f16* gB0 = Be + (size_t)(n0 + ra0) * K + ((kq ^ (ra0 & 3)) * 8);
  const f16* gB1 = Be + (size_t)(n0 + ra1) * K + ((kq ^ (ra1 & 3)) * 8);

  f32x4 zz = {0.f, 0.f, 0.f, 0.f};
  f32x4 acc[4][4];
#pragma unroll
  for (int i = 0; i < 4; ++i)
#pragma unroll
    for (int j = 0; j < 4; ++j) acc[i][j] = zz;

  int arow = wr * 64 + (lane & 15);
  int bcol = wc * 64 + (lane & 15);
  int kblk = lane >> 4;
  int aoff = arow * 32 + ((kblk ^ (arow & 3)) * 8);
  int boff = bcol * 32 + ((kblk ^ (bcol & 3)) * 8);

  auto stage = [&](int kt, int buf) {
    int ko = kt * 32;
    glds16(gA0 + ko, &sA[buf][(wid * 2 + 0) * 512]);
    glds16(gA1 + ko, &sA[buf][(wid * 2 + 1) * 512]);
    glds16(gB0 + ko, &sB[buf][(wid * 2 + 0) * 512]);
    glds16(gB1 + ko, &sB[buf][(wid * 2 + 1) * 512]);
  };

  stage(0, 0);
  __syncthreads();
  for (int kt = 0; kt < NK; ++kt) {
    int buf = kt & 1;
    if (kt + 1 < NK) stage(kt + 1, buf ^ 1);
    f16x8 af[4], bf[4];
#pragma unroll
    for (int i = 0; i < 4; ++i) {
      af[i] = *(const f16x8*)&sA[buf][aoff + i * 512];
      bf[i] = *(const f16x8*)&sB[buf][boff + i * 512];
    }
#pragma unroll
    for (int mi = 0; mi < 4; ++mi)
#pragma unroll
      for (int ni = 0; ni < 4; ++ni)
        acc[mi][ni] = __builtin_amdgcn_mfma_f32_16x16x32_f16(af[mi], bf[ni], acc[mi][ni], 0, 0, 0);
    __syncthreads();
  }

  float bv[4];
#pragma unroll
  for (int ni = 0; ni < 4; ++ni)
    bv[ni] = b1[(size_t)e * D_HID + n0 + wc * 64 + ni * 16 + (lane & 15)];
  int colb = n0 + wc * 64 + (lane & 15);
#pragma unroll
  for (int mi = 0; mi < 4; ++mi) {
#pragma unroll
    for (int r = 0; r < 4; ++r) {
      int grow = m0 + wr * 64 + mi * 16 + (lane >> 4) * 4 + r;
      float gv = gch[(size_t)grow * 8 + e];
      f16* hp = He + (size_t)grow * D_HID + colb;
#pragma unroll
      for (int ni = 0; ni < 4; ++ni) {
        float h = acc[mi][ni][r] + bv[ni];
        h = h > 0.f ? h : 0.f;
        hp[ni * 16] = (f16)(h * gv);
      }
    }
  }
}

// ---------------- GEMM2: out (+)= sum_e (gH_e) @ W2[e] + g_e*b2[e] ------------
// A fp16 [ge][hrows][2048]; Bt fp16 n-major [ge][1024][2048]
// 128x128 / 4-wave / 4x4; experts flattened into K sweep.
// cbase < 0: rows are channel-flattened (channel = grow>>12, out col base = ch*D_OUT)
__global__ __launch_bounds__(256, 2) void gemm2_kernel(
    const f16* __restrict__ H, const f16* __restrict__ Bt,
    const float* __restrict__ b2, const float* __restrict__ gch,
    float* __restrict__ out, int e0, int ge, int cbase, int accflag, int hrows) {
  const int K = D_HID;
  int m0 = blockIdx.x * 128, n0 = blockIdx.y * 128;
  int tid = threadIdx.x, wid = tid >> 6, lane = tid & 63;
  int wr = wid >> 1, wc = wid & 1;

  __shared__ __align__(16) f16 sA[2][128 * 32];
  __shared__ __align__(16) f16 sB[2][128 * 32];

  int kq = lane & 3;
  int ra0 = (wid * 2 + 0) * 16 + (lane >> 2);
  int ra1 = (wid * 2 + 1) * 16 + (lane >> 2);
  size_t oA0 = (size_t)(m0 + ra0) * K + ((kq ^ (ra0 & 3)) * 8);
  size_t oA1 = (size_t)(m0 + ra1) * K + ((kq ^ (ra1 & 3)) * 8);
  size_t oB0 = (size_t)(n0 + ra0) * K + ((kq ^ (ra0 & 3)) * 8);
  size_t oB1 = (size_t)(n0 + ra1) * K + ((kq ^ (ra1 & 3)) * 8);
  const size_t EA = (size_t)hrows * D_HID;
  const size_t EB = (size_t)D_OUT * D_HID;

  f32x4 zz = {0.f, 0.f, 0.f, 0.f};
  f32x4 acc[4][4];
#pragma unroll
  for (int i = 0; i < 4; ++i)
#pragma unroll
    for (int j = 0; j < 4; ++j) acc[i][j] = zz;

  int arow = wr * 64 + (lane & 15);
  int bcol = wc * 64 + (lane & 15);
  int kblk = lane >> 4;
  int aoff = arow * 32 + ((kblk ^ (arow & 3)) * 8);
  int boff = bcol * 32 + ((kblk ^ (bcol & 3)) * 8);

  int S = ge * (K / 32);   // experts flattened into the K sweep
  auto stage = [&](int s, int buf) {
    int ee = s >> 6; size_t ko = (size_t)(s & 63) * 32;
    glds16(H  + (size_t)ee * EA + oA0 + ko, &sA[buf][(wid * 2 + 0) * 512]);
    glds16(H  + (size_t)ee * EA + oA1 + ko, &sA[buf][(wid * 2 + 1) * 512]);
    glds16(Bt + (size_t)ee * EB + oB0 + ko, &sB[buf][(wid * 2 + 0) * 512]);
    glds16(Bt + (size_t)ee * EB + oB1 + ko, &sB[buf][(wid * 2 + 1) * 512]);
  };

  stage(0, 0);
  __syncthreads();
  for (int s = 0; s < S; ++s) {
    int buf = s & 1;
    if (s + 1 < S) stage(s + 1, buf ^ 1);
    f16x8 af[4], bf[4];
#pragma unroll
    for (int i = 0; i < 4; ++i) {
      af[i] = *(const f16x8*)&sA[buf][aoff + i * 512];
      bf[i] = *(const f16x8*)&sB[buf][boff + i * 512];
    }
#pragma unroll
    for (int mi = 0; mi < 4; ++mi)
#pragma unroll
      for (int ni = 0; ni < 4; ++ni)
        acc[mi][ni] = __builtin_amdgcn_mfma_f32_16x16x32_f16(af[mi], bf[ni], acc[mi][ni], 0, 0, 0);
    __syncthreads();
  }

  // stage b2 slice (ge x 128 cols) into now-free LDS: sb2[ee*128 + col_in_tile]
  // (safe: final K-iter __syncthreads drained all sA reads)
  float* sb2 = (float*)&sA[0][0];
  for (int i = tid; i < ge * 128; i += 256)
    sb2[i] = b2[(size_t)(e0 + (i >> 7)) * D_OUT + n0 + (i & 127)];
  __syncthreads();

  int cit = wc * 64 + (lane & 15);   // col in tile (+ ni*16)
#pragma unroll
  for (int mi = 0; mi < 4; ++mi) {
#pragma unroll
    for (int r = 0; r < 4; ++r) {
      int grow = m0 + wr * 64 + mi * 16 + (lane >> 4) * 4 + r;
      int orow, cb;
      if (cbase < 0) { orow = grow & (B_ROWS - 1); cb = (grow >> 12) * D_OUT; }
      else           { orow = grow;                cb = cbase; }
      const float* gv = gch + (size_t)grow * 8;
      float* po = out + (size_t)orow * (NCH * D_OUT) + cb + n0 + cit;
#pragma unroll
      for (int ni = 0; ni < 4; ++ni) {
        float bias = 0.f;
        for (int ee = 0; ee < ge; ++ee)
          bias += gv[e0 + ee] * sb2[ee * 128 + cit + ni * 16];
        float v = acc[mi][ni][r] + bias;
        if (accflag) po[ni * 16] += v; else po[ni * 16] = v;
      }
    }
  }
}

extern "C" void kernel_launch(void* const* d_in, const int* in_sizes, int n_in,
                              void* d_out, int out_size, void* d_ws, size_t ws_size,
                              hipStream_t stream) {
  const float* x   = (const float*)d_in[0];
  const float* y   = (const float*)d_in[1];
  const float* z   = (const float*)d_in[2];
  const float* W1  = (const float*)d_in[3];
  const float* b1  = (const float*)d_in[4];
  const float* W2  = (const float*)d_in[5];
  const float* b2  = (const float*)d_in[6];
  const float* Wg1 = (const float*)d_in[7];
  const float* Wg2 = (const float*)d_in[8];
  const float* Wg3 = (const float*)d_in[9];
  float* out = (float*)d_out;
  char* ws = (char*)d_ws;

  const size_t MB = (size_t)1 << 20;
  const size_t inpE = (size_t)B_ROWS * D_IN;               // elems per channel
  float* gates = (float*)ws;                               // 384 KB (pad to 512K)

  hipLaunchKernelGGL(gates_kernel, dim3(NCH * B_ROWS / 4), dim3(256), 0, stream,
                     x, y, z, Wg1, Wg2, Wg3, gates);

  size_t base = (512u << 10) + (size_t)MTOT * D_IN * sizeof(f16);  // gates + inp16 ~24.5 MB
  size_t perE = 56 * MB;   // 4M W1t + 4M W2t + 48M H (12288 rows) per expert

  if (ws_size >= base + perE) {
    // ------- main path: channels flattened into M=12288, EG experts resident -
    f16* inp16 = (f16*)(ws + (512u << 10));
    int EG = (int)((ws_size - base) / perE);
    if (EG > NEXP) EG = NEXP;
    f16* W1t = (f16*)(ws + base);
    f16* W2t = (f16*)(ws + base + (size_t)EG * (4 * MB));
    f16* Hb  = (f16*)(ws + base + (size_t)EG * (8 * MB));

    hipLaunchKernelGGL(conv_inp, dim3(B_ROWS * D_IN / 1024), dim3(256), 0, stream, x, inp16);
    hipLaunchKernelGGL(conv_inp, dim3(B_ROWS * D_IN / 1024), dim3(256), 0, stream, y, inp16 + inpE);
    hipLaunchKernelGGL(conv_inp, dim3(B_ROWS * D_IN / 1024), dim3(256), 0, stream, z, inp16 + 2 * inpE);

    for (int e0 = 0; e0 < NEXP; e0 += EG) {
      int ge = (EG < NEXP - e0) ? EG : (NEXP - e0);
      hipLaunchKernelGGL(conv_transpose, dim3(D_HID / 64, D_IN / 64, ge), dim3(256), 0, stream,
                         W1 + (size_t)e0 * D_IN * D_HID, W1t, D_IN, D_HID);
      hipLaunchKernelGGL(conv_transpose, dim3(D_OUT / 64, D_HID / 64, ge), dim3(256), 0, stream,
                         W2 + (size_t)e0 * D_HID * D_OUT, W2t, D_HID, D_OUT);
      // one gemm1 + one gemm2 over all 3 channels (M = 12288)
      hipLaunchKernelGGL(gemm1_kernel, dim3(MTOT / 128, 16, ge), dim3(256), 0, stream,
                         inp16, W1t, b1, gates, Hb, e0, MTOT);
      hipLaunchKernelGGL(gemm2_kernel, dim3(MTOT / 128, 8, 1), dim3(256), 0, stream,
                         Hb, W2t, b2, gates, out, e0, ge, -1, e0 > 0 ? 1 : 0, MTOT);
    }
  } else {
    // ---------------- fallback: row-chunked H, single expert resident --------
    // layout: gates(512K) | inp16buf(8M) | W1t(4M) | W2t(4M) | Hb(4M) = ~20.5MB
    const int CH = 1024;                                   // H chunk rows
    f16* inp16 = (f16*)(ws + (512u << 10));
    f16* W1t   = (f16*)(ws + (512u << 10) + 8 * MB);
    f16* W2t   = (f16*)(ws + (512u << 10) + 12 * MB);
    f16* Hb    = (f16*)(ws + (512u << 10) + 16 * MB);

    for (int c = 0; c < NCH; ++c) {
      const float* inp = c == 0 ? x : c == 1 ? y : z;
      const float* gch = gates + (size_t)c * B_ROWS * 8;
      hipLaunchKernelGGL(conv_inp, dim3(B_ROWS * D_IN / 1024), dim3(256), 0, stream, inp, inp16);
      for (int e = 0; e < NEXP; ++e) {
        hipLaunchKernelGGL(conv_transpose, dim3(D_HID / 64, D_IN / 64, 1), dim3(256), 0, stream,
                           W1 + (size_t)e * D_IN * D_HID, W1t, D_IN, D_HID);
        hipLaunchKernelGGL(conv_transpose, dim3(D_OUT / 64, D_HID / 64, 1), dim3(256), 0, stream,
                           W2 + (size_t)e * D_HID * D_OUT, W2t, D_HID, D_OUT);
        for (int mb = 0; mb < B_ROWS; mb += CH) {
          hipLaunchKernelGGL(gemm1_kernel, dim3(CH / 128, 16, 1), dim3(256), 0, stream,
                             inp16 + (size_t)mb * D_IN, W1t, b1, gch + (size_t)mb * 8,
                             Hb, e, CH);
          hipLaunchKernelGGL(gemm2_kernel, dim3(CH / 128, 8, 1), dim3(256), 0, stream,
                             Hb, W2t, b2, gch + (size_t)mb * 8,
                             out + (size_t)mb * (NCH * D_OUT), e, 1, c * D_OUT,
                             e > 0 ? 1 : 0, CH);
        }
      }
    }
  }
}